// Round 3
// baseline (155.801 us; speedup 1.0000x reference)
//
#include <hip/hip_runtime.h>
#include <math.h>

// Problem dims
constexpr int K_ = 128, J_ = 4, R_ = 32, T_ = 32, S_ = 256, A_ = 4, D_ = 64;
constexpr int Z_ = K_ * J_;
constexpr int NDF_ = 128;          // 2N
constexpr float RATE_ = 10.0f;     // 1/PRIOR_BL

constexpr int NB_NODE = K_ * T_ / 4;   // 1024 blocks, one wave per (k,t)
constexpr int NB_HYP  = Z_ / 4;        // 128 blocks, one wave per z

// Output offsets (float elements) in return order
constexpr int OFF_M1   = 0;                       // K x 33 (int->float)
constexpr int OFF_M2   = OFF_M1 + K_ * 33;
constexpr int OFF_B1   = OFF_M2 + K_ * 33;
constexpr int OFF_B2   = OFF_B1 + K_ * 33;
constexpr int OFF_EMBR = OFF_B2 + K_ * 33;        // K x 33 x 64
constexpr int OFF_LC   = OFF_EMBR + K_ * 33 * D_; // K x 31
constexpr int OFF_H    = OFF_LC + K_ * 31;
constexpr int OFF_EMBT = OFF_H + K_ * 31;         // K x 31 x 64
constexpr int OFF_LF   = OFF_EMBT + K_ * 31 * D_; // K x 31 x 256 x 4
constexpr int OFF_LPN  = OFF_LF + K_ * 31 * S_ * A_;
constexpr int OFF_LW   = OFF_LPN + K_;
constexpr int OFF_LL   = OFF_LW + K_;

// ---------- device helpers ----------

// fast 4-way logsumexp: args are max-subtracted (<=0), hardware exp/log
__device__ inline float lse4f(float a, float b, float c, float d) {
    float m = fmaxf(fmaxf(a, b), fmaxf(c, d));
    return m + __logf(__expf(a - m) + __expf(b - m) + __expf(c - m) + __expf(d - m));
}

// ---------- kernel A: node_ll (wave per (k,t)) + hyp w/ inline expm (wave per z) ----------
__global__ __launch_bounds__(256) void k_main(
    const int* __restrict__ indexes, const float* __restrict__ embt,
    const float* __restrict__ Wstat, const float* __restrict__ lf,
    const int* __restrict__ idx1_KJ, const int* __restrict__ idx2_KJ,
    const float* __restrict__ br1_KJ, const float* __restrict__ br2_KJ,
    const float* __restrict__ emb_KJD, const float* __restrict__ Wq,
    float* __restrict__ node_ll, float* __restrict__ new_node_ll,
    float* __restrict__ logP_ws) {
    int blk = blockIdx.x;
    int tid = threadIdx.x;
    int wave = tid >> 6, lane = tid & 63;

    if (blk < NB_NODE) {
        // ---- node_ll: wave handles kt = blk*4+wave; zero barriers, zero LDS ----
        int kt = blk * 4 + wave;
        int k = kt >> 5, t = kt & 31;
        int src = indexes[k];
        // stat logits: lane d holds embt[d] * Wstat[d][:], butterfly-reduce
        float e = embt[(src * T_ + t) * D_ + lane];
        const float4 w4 = *(const float4*)&Wstat[lane * 4];
        float g0 = e * w4.x, g1 = e * w4.y, g2 = e * w4.z, g3 = e * w4.w;
#pragma unroll
        for (int m = 32; m; m >>= 1) {
            g0 += __shfl_xor(g0, m, 64);
            g1 += __shfl_xor(g1, m, 64);
            g2 += __shfl_xor(g2, m, 64);
            g3 += __shfl_xor(g3, m, 64);
        }
        float lse = lse4f(g0, g1, g2, g3);
        float ls0 = g0 - lse, ls1 = g1 - lse, ls2 = g2 - lse, ls3 = g3 - lse;
        // 4 sites per lane
        const float4* fr = (const float4*)&lf[((size_t)(src * T_ + t) * S_ + lane * 4) * A_];
        double acc = 0.0;
#pragma unroll
        for (int s4 = 0; s4 < 4; ++s4) {
            float4 f = fr[s4];
            acc += (double)lse4f(f.x + ls0, f.y + ls1, f.z + ls2, f.w + ls3);
        }
#pragma unroll
        for (int m = 32; m; m >>= 1) acc += __shfl_xor(acc, m, 64);
        if (lane == 0) node_ll[kt] = (float)acc;
    } else {
        // ---- hyp: wave handles z = (blk-NB_NODE)*4 + wave ----
        int z = (blk - NB_NODE) * 4 + wave;
        int k = z >> 2;
        int src = indexes[k];
        int i1 = idx1_KJ[z], i2 = idx2_KJ[z];

        __shared__ float s_val[4][20];   // [wave][0..15]=Wq logits, [16..19]=stat logits
        __shared__ float s_logP[4][32];  // [wave][half*16 + r*4 + j]

        const float* emb = &emb_KJD[z * D_];
        if (lane < 16) {
            float lg = 0.f;
            for (int d = 0; d < D_; ++d) lg += emb[d] * Wq[d * 16 + lane];
            s_val[wave][lane] = lg;
        } else if (lane < 20) {
            int a = lane - 16;
            float lg = 0.f;
            for (int d = 0; d < D_; ++d) lg += emb[d] * Wstat[d * 4 + a];
            s_val[wave][lane] = lg;
        }
        __syncthreads();

        if (lane < 8) {
            int h = lane >> 2, r = lane & 3;
            int base = h * 4;
            // build Q (softplus off-diag, diag = -rowsum), scale: Asc = Q*br/64
            double q[16];
#pragma unroll
            for (int i = 0; i < 4; ++i) {
                double rs = 0.0;
#pragma unroll
                for (int j = 0; j < 4; ++j) {
                    if (i != j) {
                        double x = (double)s_val[wave][i * 4 + j];
                        double sp = (x > 30.0) ? x : log1p(exp(x));
                        q[i * 4 + j] = sp;
                        rs += sp;
                    }
                }
                q[i * 4 + i] = -rs;
            }
            double br = (double)(h == 0 ? br1_KJ[z] : br2_KJ[z]);
            double c = br * (1.0 / 64.0);
#pragma unroll
            for (int e2 = 0; e2 < 16; ++e2) q[e2] *= c;   // q is now Asc
            // Taylor-10, lane-local (thread owns row r of term/acc, full Asc)
            double trow[4], arow[4];
#pragma unroll
            for (int j = 0; j < 4; ++j) { trow[j] = (j == r) ? 1.0 : 0.0; arow[j] = trow[j]; }
            const double inv_n[11] = {0.0, 1.0, 0.5, 1.0 / 3.0, 0.25, 0.2,
                                      1.0 / 6.0, 1.0 / 7.0, 0.125, 1.0 / 9.0, 0.1};
#pragma unroll
            for (int n = 1; n <= 10; ++n) {
                double nt[4];
#pragma unroll
                for (int j = 0; j < 4; ++j)
                    nt[j] = (trow[0] * q[0 * 4 + j] + trow[1] * q[1 * 4 + j] +
                             trow[2] * q[2 * 4 + j] + trow[3] * q[3 * 4 + j]) * inv_n[n];
#pragma unroll
                for (int j = 0; j < 4; ++j) { trow[j] = nt[j]; arow[j] += nt[j]; }
            }
            // 6 squarings: row exchange via intra-wave shuffles (lanes base..base+3)
#pragma unroll
            for (int sq = 0; sq < 6; ++sq) {
                double nrow[4];
#pragma unroll
                for (int j = 0; j < 4; ++j) {
                    double aj = arow[j];
                    nrow[j] = arow[0] * __shfl(aj, base + 0, 64)
                            + arow[1] * __shfl(aj, base + 1, 64)
                            + arow[2] * __shfl(aj, base + 2, 64)
                            + arow[3] * __shfl(aj, base + 3, 64);
                }
#pragma unroll
                for (int j = 0; j < 4; ++j) arow[j] = nrow[j];
            }
#pragma unroll
            for (int j = 0; j < 4; ++j) {
                float pf = (float)fmax(arow[j], 1e-30);
                float lv = __logf(pf);
                s_logP[wave][h * 16 + r * 4 + j] = lv;
                logP_ws[z * 32 + h * 16 + r * 4 + j] = lv;
            }
        }
        __syncthreads();

        float sl0 = s_val[wave][16], sl1 = s_val[wave][17];
        float sl2 = s_val[wave][18], sl3 = s_val[wave][19];
        float lseS = lse4f(sl0, sl1, sl2, sl3);
        float ls0 = sl0 - lseS, ls1 = sl1 - lseS, ls2 = sl2 - lseS, ls3 = sl3 - lseS;
        float p1[16], p2[16];
#pragma unroll
        for (int i = 0; i < 16; ++i) { p1[i] = s_logP[wave][i]; p2[i] = s_logP[wave][16 + i]; }
        const float4* f1p = (const float4*)&lf[((size_t)(src * T_ + i1) * S_ + lane * 4) * A_];
        const float4* f2p = (const float4*)&lf[((size_t)(src * T_ + i2) * S_ + lane * 4) * A_];
        double acc = 0.0;
#pragma unroll
        for (int s4 = 0; s4 < 4; ++s4) {
            float4 f = f1p[s4];
            float4 g = f2p[s4];
            float nlf[4];
#pragma unroll
            for (int a = 0; a < 4; ++a) {
                float t1 = lse4f(p1[a * 4 + 0] + f.x, p1[a * 4 + 1] + f.y,
                                 p1[a * 4 + 2] + f.z, p1[a * 4 + 3] + f.w);
                float t2 = lse4f(p2[a * 4 + 0] + g.x, p2[a * 4 + 1] + g.y,
                                 p2[a * 4 + 2] + g.z, p2[a * 4 + 3] + g.w);
                nlf[a] = t1 + t2;
            }
            acc += (double)lse4f(nlf[0] + ls0, nlf[1] + ls1, nlf[2] + ls2, nlf[3] + ls3);
        }
#pragma unroll
        for (int m = 32; m; m >>= 1) acc += __shfl_xor(acc, m, 64);
        if (lane == 0) new_node_ll[z] = (float)acc;
    }
}

// ---------- kernel B: weights, selection, scalar outputs ----------
__global__ __launch_bounds__(64) void k_finalize(
    const int* __restrict__ indexes, const int* __restrict__ lc_Kt,
    const float* __restrict__ b1_Kr, const float* __restrict__ b2_Kr,
    const float* __restrict__ logpi_K, const int* __restrict__ idx1_KJ,
    const int* __restrict__ idx2_KJ, const float* __restrict__ br1_KJ,
    const float* __restrict__ br2_KJ, const float* __restrict__ logvp_KJ,
    const float* __restrict__ gumbel_KJ, const float* __restrict__ ldf,
    const float* __restrict__ node_ll, const float* __restrict__ new_node_ll,
    float* __restrict__ out, int* __restrict__ sub_idx) {
    int k = blockIdx.x;
    int lane = threadIdx.x;
    int src = indexes[k];
    double nll = 0.0, topo = 0.0, sb1 = 0.0, sb2 = 0.0;
    int cnt = 0;
    if (lane < T_) {
        nll = (double)node_ll[k * T_ + lane];
        int lc = lc_Kt[src * T_ + lane];
        int di = 2 * lc - 3; di = max(0, min(NDF_ - 1, di));
        topo = (double)ldf[di];
        cnt = (lc > 1) ? 1 : 0;
        sb1 = (double)b1_Kr[src * R_ + lane];
        sb2 = (double)b2_Kr[src * R_ + lane];
    }
    for (int o = 32; o > 0; o >>= 1) {
        nll += __shfl_down(nll, o, 64);
        topo += __shfl_down(topo, o, 64);
        sb1 += __shfl_down(sb1, o, 64);
        sb2 += __shfl_down(sb2, o, 64);
        cnt += __shfl_down(cnt, o, 64);
    }
    if (lane == 0) {
        double total_ll = nll, base_topo = -topo;
        const double lr = log(10.0);
        double lw[4], lpn[4], llik[4];
        for (int j = 0; j < J_; ++j) {
            int z = k * J_ + j;
            int i1 = idx1_KJ[z], i2 = idx2_KJ[z];
            int lc1 = lc_Kt[src * T_ + i1], lc2 = lc_Kt[src * T_ + i2];
            int nlc = lc1 + lc2;
            double loglik = total_ll - (double)node_ll[k * T_ + i1]
                                     - (double)node_ll[k * T_ + i2]
                                     + (double)new_node_ll[z];
            double lbp = 66.0 * lr
                       - (double)RATE_ * (sb1 + (double)br1_KJ[z] + sb2 + (double)br2_KJ[z]);
            int d1 = max(0, min(NDF_ - 1, 2 * lc1 - 3));
            int d2 = max(0, min(NDF_ - 1, 2 * lc2 - 3));
            int dn = max(0, min(NDF_ - 1, 2 * nlc - 3));
            double lt = base_topo + (double)ldf[d1] + (double)ldf[d2] - (double)ldf[dn];
            int cntj = cnt - ((lc1 > 1) ? 1 : 0) - ((lc2 > 1) ? 1 : 0) + 1;
            double lvm = log((double)cntj);
            lpn[j] = loglik + lbp + lt;
            llik[j] = loglik;
            lw[j] = lpn[j] - (double)logpi_K[src] + lvm - (double)logvp_KJ[z];
        }
        double m = fmax(fmax(lw[0], lw[1]), fmax(lw[2], lw[3]));
        double ssum = exp(lw[0] - m) + exp(lw[1] - m) + exp(lw[2] - m) + exp(lw[3] - m);
        double logw = m + log(ssum) - log((double)J_);
        int best = 0;
        double bv = lw[0] + (double)gumbel_KJ[k * J_ + 0];
        for (int j = 1; j < J_; ++j) {
            double v = lw[j] + (double)gumbel_KJ[k * J_ + j];
            if (v > bv) { bv = v; best = j; }
        }
        out[OFF_LPN + k] = (float)lpn[best];
        out[OFF_LW + k] = (float)logw;
        out[OFF_LL + k] = (float)llik[best];
        sub_idx[k] = best;
    }
}

// ---------- kernel C: assemble all big outputs for the selected proposal ----------
__global__ __launch_bounds__(256) void k_output(
    const int* __restrict__ indexes, const int* __restrict__ m1_Kr,
    const int* __restrict__ m2_Kr, const float* __restrict__ b1_Kr,
    const float* __restrict__ b2_Kr, const float* __restrict__ embr,
    const int* __restrict__ lc_Kt, const int* __restrict__ h_Kt,
    const float* __restrict__ embt, const float* __restrict__ lf,
    const int* __restrict__ idx1_KJ, const int* __restrict__ idx2_KJ,
    const float* __restrict__ br1_KJ, const float* __restrict__ br2_KJ,
    const float* __restrict__ emb_KJD, const float* __restrict__ logP_ws,
    const int* __restrict__ sub_idx, float* __restrict__ out) {
    int blk = blockIdx.x;
    int k = blk >> 5, part = blk & 31;
    int tid = threadIdx.x;
    int src = indexes[k];
    int sub = sub_idx[k];
    int z = k * J_ + sub;
    int i1 = idx1_KJ[z], i2 = idx2_KJ[z];
    int mn = min(i1, i2), mx = max(i1, i2);

    if (part < 30) {
        int st = part;
        if (st >= mn) ++st;
        if (st >= mx) ++st;
        const float4 v = *(const float4*)&lf[((size_t)(src * T_ + st) * S_ + tid) * A_];
        *(float4*)&out[OFF_LF + ((size_t)(k * 31 + part) * S_ + tid) * A_] = v;
    } else if (part == 30) {
        __shared__ float s_logP[32];
        if (tid < 32) s_logP[tid] = logP_ws[z * 32 + tid];
        __syncthreads();
        const float4 f1 = *(const float4*)&lf[((size_t)(src * T_ + i1) * S_ + tid) * A_];
        const float4 f2 = *(const float4*)&lf[((size_t)(src * T_ + i2) * S_ + tid) * A_];
        float4 o4;
        float nlf[4];
#pragma unroll
        for (int a = 0; a < 4; ++a) {
            float t1 = lse4f(s_logP[a * 4 + 0] + f1.x, s_logP[a * 4 + 1] + f1.y,
                             s_logP[a * 4 + 2] + f1.z, s_logP[a * 4 + 3] + f1.w);
            float t2 = lse4f(s_logP[16 + a * 4 + 0] + f2.x, s_logP[16 + a * 4 + 1] + f2.y,
                             s_logP[16 + a * 4 + 2] + f2.z, s_logP[16 + a * 4 + 3] + f2.w);
            nlf[a] = t1 + t2;
        }
        o4.x = nlf[0]; o4.y = nlf[1]; o4.z = nlf[2]; o4.w = nlf[3];
        *(float4*)&out[OFF_LF + ((size_t)(k * 31 + 30) * S_ + tid) * A_] = o4;
    } else {
        // part == 31: all small outputs for particle k
        for (int i = tid; i < 33; i += 256) {
            float v1, v2, fb1, fb2;
            if (i < 32) {
                v1 = (float)m1_Kr[src * R_ + i];
                v2 = (float)m2_Kr[src * R_ + i];
                fb1 = b1_Kr[src * R_ + i];
                fb2 = b2_Kr[src * R_ + i];
            } else {
                v1 = (float)i1; v2 = (float)i2;
                fb1 = br1_KJ[z]; fb2 = br2_KJ[z];
            }
            out[OFF_M1 + k * 33 + i] = v1;
            out[OFF_M2 + k * 33 + i] = v2;
            out[OFF_B1 + k * 33 + i] = fb1;
            out[OFF_B2 + k * 33 + i] = fb2;
        }
        for (int i = tid; i < 33 * D_; i += 256) {
            int r = i >> 6, d = i & 63;
            float v = (r < 32) ? embr[(src * R_ + r) * D_ + d] : emb_KJD[z * D_ + d];
            out[OFF_EMBR + k * 33 * D_ + i] = v;
        }
        for (int i = tid; i < 31; i += 256) {
            int lcv, hv;
            if (i < 30) {
                int st = i;
                if (st >= mn) ++st;
                if (st >= mx) ++st;
                lcv = lc_Kt[src * T_ + st];
                hv = h_Kt[src * T_ + st];
            } else {
                lcv = lc_Kt[src * T_ + i1] + lc_Kt[src * T_ + i2];
                int h1 = h_Kt[src * T_ + i1], h2 = h_Kt[src * T_ + i2];
                int hmn = min(h1, h2), hmx = max(h1, h2);
                unsigned int u = ((unsigned int)hmn * 1000003u + (unsigned int)hmx) * 40503u
                                 + 2531011u;
                hv = (int)u;  // int32 wraparound, matches JAX
            }
            out[OFF_LC + k * 31 + i] = (float)lcv;
            out[OFF_H + k * 31 + i] = (float)hv;
        }
        for (int i = tid; i < 31 * D_; i += 256) {
            int t = i >> 6, d = i & 63;
            float v;
            if (t < 30) {
                int st = t;
                if (st >= mn) ++st;
                if (st >= mx) ++st;
                v = embt[(src * T_ + st) * D_ + d];
            } else {
                v = emb_KJD[z * D_ + d];
            }
            out[OFF_EMBT + k * 31 * D_ + i] = v;
        }
    }
}

extern "C" void kernel_launch(void* const* d_in, const int* in_sizes, int n_in,
                              void* d_out, int out_size, void* d_ws, size_t ws_size,
                              hipStream_t stream) {
    const int* indexes   = (const int*)d_in[0];
    const int* m1_Kr     = (const int*)d_in[1];
    const int* m2_Kr     = (const int*)d_in[2];
    const float* b1_Kr   = (const float*)d_in[3];
    const float* b2_Kr   = (const float*)d_in[4];
    const float* embr    = (const float*)d_in[5];
    const int* lc_Kt     = (const int*)d_in[6];
    const int* h_Kt      = (const int*)d_in[7];
    const float* embt    = (const float*)d_in[8];
    const float* lf      = (const float*)d_in[9];
    const float* logpi_K = (const float*)d_in[10];
    const int* idx1_KJ   = (const int*)d_in[11];
    const int* idx2_KJ   = (const int*)d_in[12];
    const float* br1_KJ  = (const float*)d_in[13];
    const float* br2_KJ  = (const float*)d_in[14];
    const float* emb_KJD = (const float*)d_in[15];
    const float* logvp_KJ = (const float*)d_in[16];
    const float* gumbel_KJ = (const float*)d_in[17];
    const float* Wq      = (const float*)d_in[18];
    const float* Wstat   = (const float*)d_in[19];
    const float* ldf     = (const float*)d_in[20];

    float* out = (float*)d_out;
    float* ws_f = (float*)d_ws;
    float* new_node_ll = ws_f;                          // Z_
    float* node_ll = ws_f + Z_;                         // K_*T_
    int* sub_idx = (int*)(ws_f + Z_ + K_ * T_);         // K_ ints
    float* logP_ws = ws_f + Z_ + K_ * T_ + K_;          // Z_*32

    k_main<<<NB_NODE + NB_HYP, 256, 0, stream>>>(
        indexes, embt, Wstat, lf, idx1_KJ, idx2_KJ, br1_KJ, br2_KJ, emb_KJD, Wq,
        node_ll, new_node_ll, logP_ws);
    k_finalize<<<K_, 64, 0, stream>>>(indexes, lc_Kt, b1_Kr, b2_Kr, logpi_K, idx1_KJ,
                                      idx2_KJ, br1_KJ, br2_KJ, logvp_KJ, gumbel_KJ,
                                      ldf, node_ll, new_node_ll, out, sub_idx);
    k_output<<<K_ * 32, 256, 0, stream>>>(indexes, m1_Kr, m2_Kr, b1_Kr, b2_Kr, embr,
                                          lc_Kt, h_Kt, embt, lf, idx1_KJ, idx2_KJ,
                                          br1_KJ, br2_KJ, emb_KJD, logP_ws, sub_idx, out);
}

// Round 4
// 146.555 us; speedup vs baseline: 1.0631x; 1.0631x over previous
//
#include <hip/hip_runtime.h>
#include <math.h>

// Problem dims
constexpr int K_ = 128, J_ = 4, R_ = 32, T_ = 32, S_ = 256, A_ = 4, D_ = 64;
constexpr int NDF_ = 128;          // 2N
constexpr float RATE_ = 10.0f;     // 1/PRIOR_BL

// Output offsets (float elements) in return order
constexpr int OFF_M1   = 0;                       // K x 33 (int->float)
constexpr int OFF_M2   = OFF_M1 + K_ * 33;
constexpr int OFF_B1   = OFF_M2 + K_ * 33;
constexpr int OFF_B2   = OFF_B1 + K_ * 33;
constexpr int OFF_EMBR = OFF_B2 + K_ * 33;        // K x 33 x 64
constexpr int OFF_LC   = OFF_EMBR + K_ * 33 * D_; // K x 31
constexpr int OFF_H    = OFF_LC + K_ * 31;
constexpr int OFF_EMBT = OFF_H + K_ * 31;         // K x 31 x 64
constexpr int OFF_LF   = OFF_EMBT + K_ * 31 * D_; // K x 31 x 256 x 4
constexpr int OFF_LPN  = OFF_LF + K_ * 31 * S_ * A_;
constexpr int OFF_LW   = OFF_LPN + K_;
constexpr int OFF_LL   = OFF_LW + K_;

// fast 4-way logsumexp: args are max-subtracted (<=0), hardware exp/log
__device__ inline float lse4f(float a, float b, float c, float d) {
    float m = fmaxf(fmaxf(a, b), fmaxf(c, d));
    return m + __logf(__expf(a - m) + __expf(b - m) + __expf(c - m) + __expf(d - m));
}

// ---------- single fused kernel: block k owns particle k ----------
__global__ __launch_bounds__(256) void k_all(
    const int* __restrict__ indexes, const int* __restrict__ m1_Kr,
    const int* __restrict__ m2_Kr, const float* __restrict__ b1_Kr,
    const float* __restrict__ b2_Kr, const float* __restrict__ embr,
    const int* __restrict__ lc_Kt, const int* __restrict__ h_Kt,
    const float* __restrict__ embt, const float* __restrict__ lf,
    const float* __restrict__ logpi_K, const int* __restrict__ idx1_KJ,
    const int* __restrict__ idx2_KJ, const float* __restrict__ br1_KJ,
    const float* __restrict__ br2_KJ, const float* __restrict__ emb_KJD,
    const float* __restrict__ logvp_KJ, const float* __restrict__ gumbel_KJ,
    const float* __restrict__ Wq, const float* __restrict__ Wstat,
    const float* __restrict__ ldf, float* __restrict__ out) {
    int k = blockIdx.x;
    int tid = threadIdx.x;
    int w = tid >> 6, lane = tid & 63;
    int src = indexes[k];

    __shared__ float s_node_ll[T_];
    __shared__ float s_new_ll[J_];
    __shared__ float s_logP[J_][32];
    __shared__ int s_sub;

    // ================= Phase 1: node_ll, wave w handles t = i*4 + w =================
#pragma unroll
    for (int i = 0; i < 8; ++i) {
        int t = i * 4 + w;
        float e = embt[(src * T_ + t) * D_ + lane];
        const float4 w4 = *(const float4*)&Wstat[lane * 4];
        float g0 = e * w4.x, g1 = e * w4.y, g2 = e * w4.z, g3 = e * w4.w;
#pragma unroll
        for (int m = 32; m; m >>= 1) {
            g0 += __shfl_xor(g0, m, 64);
            g1 += __shfl_xor(g1, m, 64);
            g2 += __shfl_xor(g2, m, 64);
            g3 += __shfl_xor(g3, m, 64);
        }
        float lse = lse4f(g0, g1, g2, g3);
        float ls0 = g0 - lse, ls1 = g1 - lse, ls2 = g2 - lse, ls3 = g3 - lse;
        const float4* fr = (const float4*)&lf[(size_t)(src * T_ + t) * S_ * A_];
        double acc = 0.0;
#pragma unroll
        for (int s4 = 0; s4 < 4; ++s4) {
            float4 f = fr[s4 * 64 + lane];   // coalesced: 1KB per instruction
            acc += (double)lse4f(f.x + ls0, f.y + ls1, f.z + ls2, f.w + ls3);
        }
#pragma unroll
        for (int m = 32; m; m >>= 1) acc += __shfl_xor(acc, m, 64);
        if (lane == 0) s_node_ll[t] = (float)acc;
    }

    // ================= Phase 2: hyp, wave w handles proposal z = k*4 + w ============
    {
        int z = k * J_ + w;
        int i1 = idx1_KJ[z], i2 = idx2_KJ[z];

        // 20 logits (16 Wq + 4 Wstat) via one butterfly: lane d owns emb[d]*W[d,:]
        float emb_d = emb_KJD[z * D_ + lane];
        float lg[20];
        const float4* wqr = (const float4*)&Wq[lane * 16];
        float4 q0 = wqr[0], q1 = wqr[1], q2 = wqr[2], q3 = wqr[3];
        lg[0] = emb_d * q0.x;  lg[1] = emb_d * q0.y;  lg[2] = emb_d * q0.z;  lg[3] = emb_d * q0.w;
        lg[4] = emb_d * q1.x;  lg[5] = emb_d * q1.y;  lg[6] = emb_d * q1.z;  lg[7] = emb_d * q1.w;
        lg[8] = emb_d * q2.x;  lg[9] = emb_d * q2.y;  lg[10] = emb_d * q2.z; lg[11] = emb_d * q2.w;
        lg[12] = emb_d * q3.x; lg[13] = emb_d * q3.y; lg[14] = emb_d * q3.z; lg[15] = emb_d * q3.w;
        const float4 ws4 = *(const float4*)&Wstat[lane * 4];
        lg[16] = emb_d * ws4.x; lg[17] = emb_d * ws4.y; lg[18] = emb_d * ws4.z; lg[19] = emb_d * ws4.w;
#pragma unroll
        for (int m = 32; m; m >>= 1) {
#pragma unroll
            for (int p = 0; p < 20; ++p) lg[p] += __shfl_xor(lg[p], m, 64);
        }

        float lseS = lse4f(lg[16], lg[17], lg[18], lg[19]);
        float ls0 = lg[16] - lseS, ls1 = lg[17] - lseS, ls2 = lg[18] - lseS, ls3 = lg[19] - lseS;

        // expm (f32, fixed 2^-6 scaling + Taylor-10 + 6 squarings) on lanes 0..7
        float lv[4] = {0.f, 0.f, 0.f, 0.f};
        if (lane < 8) {
            int h = lane >> 2, r = lane & 3, base = h * 4;
            float q[16];
#pragma unroll
            for (int i = 0; i < 4; ++i) {
                float rs = 0.f;
#pragma unroll
                for (int j = 0; j < 4; ++j) {
                    if (i != j) {
                        float x = lg[i * 4 + j];
                        float sp = (x > 15.f) ? x : log1pf(__expf(x));
                        q[i * 4 + j] = sp;
                        rs += sp;
                    }
                }
                q[i * 4 + i] = -rs;
            }
            float br = (h == 0) ? br1_KJ[z] : br2_KJ[z];
            float c = br * (1.f / 64.f);
#pragma unroll
            for (int e2 = 0; e2 < 16; ++e2) q[e2] *= c;
            float trow[4], arow[4];
#pragma unroll
            for (int j = 0; j < 4; ++j) { trow[j] = (j == r) ? 1.f : 0.f; arow[j] = trow[j]; }
            const float inv_n[11] = {0.f, 1.f, 0.5f, 1.f / 3.f, 0.25f, 0.2f,
                                     1.f / 6.f, 1.f / 7.f, 0.125f, 1.f / 9.f, 0.1f};
#pragma unroll
            for (int n = 1; n <= 10; ++n) {
                float nt[4];
#pragma unroll
                for (int j = 0; j < 4; ++j)
                    nt[j] = (trow[0] * q[0 * 4 + j] + trow[1] * q[1 * 4 + j] +
                             trow[2] * q[2 * 4 + j] + trow[3] * q[3 * 4 + j]) * inv_n[n];
#pragma unroll
                for (int j = 0; j < 4; ++j) { trow[j] = nt[j]; arow[j] += nt[j]; }
            }
#pragma unroll
            for (int sq = 0; sq < 6; ++sq) {
                float nrow[4];
#pragma unroll
                for (int j = 0; j < 4; ++j) {
                    float aj = arow[j];
                    nrow[j] = arow[0] * __shfl(aj, base + 0, 64)
                            + arow[1] * __shfl(aj, base + 1, 64)
                            + arow[2] * __shfl(aj, base + 2, 64)
                            + arow[3] * __shfl(aj, base + 3, 64);
                }
#pragma unroll
                for (int j = 0; j < 4; ++j) arow[j] = nrow[j];
            }
#pragma unroll
            for (int j = 0; j < 4; ++j) {
                lv[j] = __logf(fmaxf(arow[j], 1e-30f));
                s_logP[w][h * 16 + r * 4 + j] = lv[j];
            }
        }
        // broadcast logP to all lanes (p1 rows live in lanes 0..3, p2 in lanes 4..7)
        float p1[16], p2[16];
#pragma unroll
        for (int r = 0; r < 4; ++r) {
#pragma unroll
            for (int j = 0; j < 4; ++j) {
                p1[r * 4 + j] = __shfl(lv[j], r, 64);
                p2[r * 4 + j] = __shfl(lv[j], 4 + r, 64);
            }
        }
        // new-node log-lik over sites
        const float4* f1p = (const float4*)&lf[(size_t)(src * T_ + i1) * S_ * A_];
        const float4* f2p = (const float4*)&lf[(size_t)(src * T_ + i2) * S_ * A_];
        double acc = 0.0;
#pragma unroll
        for (int s4 = 0; s4 < 4; ++s4) {
            float4 f = f1p[s4 * 64 + lane];
            float4 g = f2p[s4 * 64 + lane];
            float nlf[4];
#pragma unroll
            for (int a = 0; a < 4; ++a) {
                float t1 = lse4f(p1[a * 4 + 0] + f.x, p1[a * 4 + 1] + f.y,
                                 p1[a * 4 + 2] + f.z, p1[a * 4 + 3] + f.w);
                float t2 = lse4f(p2[a * 4 + 0] + g.x, p2[a * 4 + 1] + g.y,
                                 p2[a * 4 + 2] + g.z, p2[a * 4 + 3] + g.w);
                nlf[a] = t1 + t2;
            }
            acc += (double)lse4f(nlf[0] + ls0, nlf[1] + ls1, nlf[2] + ls2, nlf[3] + ls3);
        }
#pragma unroll
        for (int m = 32; m; m >>= 1) acc += __shfl_xor(acc, m, 64);
        if (lane == 0) s_new_ll[w] = (float)acc;
    }
    __syncthreads();

    // ================= Phase 3: finalize (wave 0) =================
    if (w == 0) {
        double nll = 0.0, topo = 0.0, sb1 = 0.0, sb2 = 0.0;
        int cnt = 0;
        if (lane < T_) {
            nll = (double)s_node_ll[lane];
            int lc = lc_Kt[src * T_ + lane];
            int di = 2 * lc - 3; di = max(0, min(NDF_ - 1, di));
            topo = (double)ldf[di];
            cnt = (lc > 1) ? 1 : 0;
            sb1 = (double)b1_Kr[src * R_ + lane];
            sb2 = (double)b2_Kr[src * R_ + lane];
        }
        for (int o = 32; o > 0; o >>= 1) {
            nll += __shfl_down(nll, o, 64);
            topo += __shfl_down(topo, o, 64);
            sb1 += __shfl_down(sb1, o, 64);
            sb2 += __shfl_down(sb2, o, 64);
            cnt += __shfl_down(cnt, o, 64);
        }
        if (lane == 0) {
            double total_ll = nll, base_topo = -topo;
            const double lr = log(10.0);
            double lw[4], lpn[4], llik[4];
            for (int j = 0; j < J_; ++j) {
                int z = k * J_ + j;
                int i1 = idx1_KJ[z], i2 = idx2_KJ[z];
                int lc1 = lc_Kt[src * T_ + i1], lc2 = lc_Kt[src * T_ + i2];
                int nlc = lc1 + lc2;
                double loglik = total_ll - (double)s_node_ll[i1] - (double)s_node_ll[i2]
                              + (double)s_new_ll[j];
                double lbp = 66.0 * lr
                           - (double)RATE_ * (sb1 + (double)br1_KJ[z] + sb2 + (double)br2_KJ[z]);
                int d1 = max(0, min(NDF_ - 1, 2 * lc1 - 3));
                int d2 = max(0, min(NDF_ - 1, 2 * lc2 - 3));
                int dn = max(0, min(NDF_ - 1, 2 * nlc - 3));
                double lt = base_topo + (double)ldf[d1] + (double)ldf[d2] - (double)ldf[dn];
                int cntj = cnt - ((lc1 > 1) ? 1 : 0) - ((lc2 > 1) ? 1 : 0) + 1;
                double lvm = log((double)cntj);
                lpn[j] = loglik + lbp + lt;
                llik[j] = loglik;
                lw[j] = lpn[j] - (double)logpi_K[src] + lvm - (double)logvp_KJ[z];
            }
            double m = fmax(fmax(lw[0], lw[1]), fmax(lw[2], lw[3]));
            double ssum = exp(lw[0] - m) + exp(lw[1] - m) + exp(lw[2] - m) + exp(lw[3] - m);
            double logw = m + log(ssum) - log((double)J_);
            int best = 0;
            double bv = lw[0] + (double)gumbel_KJ[k * J_ + 0];
            for (int j = 1; j < J_; ++j) {
                double v = lw[j] + (double)gumbel_KJ[k * J_ + j];
                if (v > bv) { bv = v; best = j; }
            }
            out[OFF_LPN + k] = (float)lpn[best];
            out[OFF_LW + k] = (float)logw;
            out[OFF_LL + k] = (float)llik[best];
            s_sub = best;
        }
    }
    __syncthreads();

    // ================= Phase 4: outputs for the selected proposal =================
    int sub = s_sub;
    int zs = k * J_ + sub;
    int si1 = idx1_KJ[zs], si2 = idx2_KJ[zs];
    int mn = min(si1, si2), mx = max(si1, si2);

    // 4b: new Felsenstein row (tid = site)
    {
        float P1[16], P2[16];
#pragma unroll
        for (int i = 0; i < 16; ++i) { P1[i] = s_logP[sub][i]; P2[i] = s_logP[sub][16 + i]; }
        const float4 f1 = *(const float4*)&lf[((size_t)(src * T_ + si1) * S_ + tid) * A_];
        const float4 f2 = *(const float4*)&lf[((size_t)(src * T_ + si2) * S_ + tid) * A_];
        float4 o4;
#pragma unroll
        for (int a = 0; a < 4; ++a) {
            float t1 = lse4f(P1[a * 4 + 0] + f1.x, P1[a * 4 + 1] + f1.y,
                             P1[a * 4 + 2] + f1.z, P1[a * 4 + 3] + f1.w);
            float t2 = lse4f(P2[a * 4 + 0] + f2.x, P2[a * 4 + 1] + f2.y,
                             P2[a * 4 + 2] + f2.z, P2[a * 4 + 3] + f2.w);
            ((float*)&o4)[a] = t1 + t2;
        }
        *(float4*)&out[OFF_LF + ((size_t)(k * 31 + 30) * S_ + tid) * A_] = o4;
    }
    // 4a: 30 kept Felsenstein rows (tid = site)
    for (int row = 0; row < 30; ++row) {
        int st = row;
        if (st >= mn) ++st;
        if (st >= mx) ++st;
        const float4 v = *(const float4*)&lf[((size_t)(src * T_ + st) * S_ + tid) * A_];
        *(float4*)&out[OFF_LF + ((size_t)(k * 31 + row) * S_ + tid) * A_] = v;
    }
    // 4c: small outputs
    for (int i = tid; i < 33; i += 256) {
        float v1, v2, fb1, fb2;
        if (i < 32) {
            v1 = (float)m1_Kr[src * R_ + i];
            v2 = (float)m2_Kr[src * R_ + i];
            fb1 = b1_Kr[src * R_ + i];
            fb2 = b2_Kr[src * R_ + i];
        } else {
            v1 = (float)si1; v2 = (float)si2;
            fb1 = br1_KJ[zs]; fb2 = br2_KJ[zs];
        }
        out[OFF_M1 + k * 33 + i] = v1;
        out[OFF_M2 + k * 33 + i] = v2;
        out[OFF_B1 + k * 33 + i] = fb1;
        out[OFF_B2 + k * 33 + i] = fb2;
    }
    for (int i = tid; i < 33 * D_; i += 256) {
        int r = i >> 6, d = i & 63;
        float v = (r < 32) ? embr[(src * R_ + r) * D_ + d] : emb_KJD[zs * D_ + d];
        out[OFF_EMBR + k * 33 * D_ + i] = v;
    }
    for (int i = tid; i < 31; i += 256) {
        int lcv, hv;
        if (i < 30) {
            int st = i;
            if (st >= mn) ++st;
            if (st >= mx) ++st;
            lcv = lc_Kt[src * T_ + st];
            hv = h_Kt[src * T_ + st];
        } else {
            lcv = lc_Kt[src * T_ + si1] + lc_Kt[src * T_ + si2];
            int h1 = h_Kt[src * T_ + si1], h2 = h_Kt[src * T_ + si2];
            int hmn = min(h1, h2), hmx = max(h1, h2);
            unsigned int u = ((unsigned int)hmn * 1000003u + (unsigned int)hmx) * 40503u
                             + 2531011u;
            hv = (int)u;  // int32 wraparound, matches JAX
        }
        out[OFF_LC + k * 31 + i] = (float)lcv;
        out[OFF_H + k * 31 + i] = (float)hv;
    }
    for (int i = tid; i < 31 * D_; i += 256) {
        int t = i >> 6, d = i & 63;
        float v;
        if (t < 30) {
            int st = t;
            if (st >= mn) ++st;
            if (st >= mx) ++st;
            v = embt[(src * T_ + st) * D_ + d];
        } else {
            v = emb_KJD[zs * D_ + d];
        }
        out[OFF_EMBT + k * 31 * D_ + i] = v;
    }
}

extern "C" void kernel_launch(void* const* d_in, const int* in_sizes, int n_in,
                              void* d_out, int out_size, void* d_ws, size_t ws_size,
                              hipStream_t stream) {
    const int* indexes   = (const int*)d_in[0];
    const int* m1_Kr     = (const int*)d_in[1];
    const int* m2_Kr     = (const int*)d_in[2];
    const float* b1_Kr   = (const float*)d_in[3];
    const float* b2_Kr   = (const float*)d_in[4];
    const float* embr    = (const float*)d_in[5];
    const int* lc_Kt     = (const int*)d_in[6];
    const int* h_Kt      = (const int*)d_in[7];
    const float* embt    = (const float*)d_in[8];
    const float* lf      = (const float*)d_in[9];
    const float* logpi_K = (const float*)d_in[10];
    const int* idx1_KJ   = (const int*)d_in[11];
    const int* idx2_KJ   = (const int*)d_in[12];
    const float* br1_KJ  = (const float*)d_in[13];
    const float* br2_KJ  = (const float*)d_in[14];
    const float* emb_KJD = (const float*)d_in[15];
    const float* logvp_KJ = (const float*)d_in[16];
    const float* gumbel_KJ = (const float*)d_in[17];
    const float* Wq      = (const float*)d_in[18];
    const float* Wstat   = (const float*)d_in[19];
    const float* ldf     = (const float*)d_in[20];
    float* out = (float*)d_out;

    k_all<<<K_, 256, 0, stream>>>(indexes, m1_Kr, m2_Kr, b1_Kr, b2_Kr, embr,
                                  lc_Kt, h_Kt, embt, lf, logpi_K, idx1_KJ, idx2_KJ,
                                  br1_KJ, br2_KJ, emb_KJD, logvp_KJ, gumbel_KJ,
                                  Wq, Wstat, ldf, out);
}